// Round 2
// baseline (10124.783 us; speedup 1.0000x reference)
//
#include <hip/hip_runtime.h>
#include <math.h>

#define BB 16
#define NN 4096
#define SS 512
#define KK 32
#define NPIX (BB*SS*KK)          /* 262144 pixels (b,s,k) */
#define NGRP (BB*SS)             /* 8192 groups */

static constexpr float R2F  = (float)0.16000000000000003;  // RADIUS**2 as f32
static constexpr float EPSF = 1e-5f;

// ---------------- workspace layout (bytes) ----------------
constexpr size_t OFF_NXYZ = 0;                     // B*S*3 f32        = 98304
constexpr size_t OFF_GRP  = 98304;                 // B*S*NS i32       = 1048576
constexpr size_t OFF_P1   = 98304 + 1048576;       // 2*64*32 f64      = 32768
constexpr size_t OFF_P2   = OFF_P1 + 32768;
constexpr size_t OFF_P3   = OFF_P2 + 32768;        // 2*128*32 f64     = 65536
constexpr size_t OFF_MR1  = OFF_P3 + 65536;        // 64*2 f32
constexpr size_t OFF_MR2  = OFF_MR1 + 512;
constexpr size_t OFF_MR3  = OFF_MR2 + 512;         // 128*2 f32
constexpr size_t OFF_Z    = 2*1024*1024;
constexpr size_t ZB64     = (size_t)64*NPIX*4;     // 67108864
constexpr size_t NEED_WS  = OFF_Z + 4*ZB64;        // z1(64)+z2(64)+z3(128) = 270532608

// ======================= FPS =======================
// 512 threads (8 waves), 8 points/thread. Double-buffered cross-wave
// reduction -> ONE __syncthreads per step: step s reads redv[s&1]; the
// next write to that buffer is at step s+2, separated by step s+1's
// barrier, so no WAR barrier is needed.
__global__ __launch_bounds__(512) void fps_kernel(const float* __restrict__ xyz,
        float* __restrict__ out0, float* __restrict__ nxyz){
  const int b = blockIdx.x;
  const float* xb = xyz + (size_t)b*3*NN;
  __shared__ float sx[NN], sy[NN], sz[NN];
  __shared__ float redv[2][8];
  __shared__ int   redi[2][8];
  const int t = threadIdx.x;
  float rx[8], ry[8], rz[8], rd[8];
#pragma unroll
  for (int j=0;j<8;j++){
    int i = t + 512*j;
    float x = xb[i], y = xb[NN+i], z = xb[2*NN+i];
    rx[j]=x; ry[j]=y; rz[j]=z;
    sx[i]=x; sy[i]=y; sz[i]=z;
    rd[j]=1e10f;
  }
  __syncthreads();
  int far = 0;
  const int lane = t & 63, wv = t >> 6;
  for (int s=0;s<SS;s++){
    const int buf = s & 1;
    float cx = sx[far], cy = sy[far], cz = sz[far];
    if (t==0){
      nxyz[(b*SS+s)*3+0]=cx; nxyz[(b*SS+s)*3+1]=cy; nxyz[(b*SS+s)*3+2]=cz;
      out0[(b*3+0)*SS+s]=cx; out0[(b*3+1)*SS+s]=cy; out0[(b*3+2)*SS+s]=cz;
    }
    float bv=-1.0f; int bi=0;
#pragma unroll
    for (int j=0;j<8;j++){
      float dx=__fsub_rn(rx[j],cx), dy=__fsub_rn(ry[j],cy), dz=__fsub_rn(rz[j],cz);
      float d2=__fadd_rn(__fadd_rn(__fmul_rn(dx,dx),__fmul_rn(dy,dy)),__fmul_rn(dz,dz));
      float nd=fminf(rd[j],d2);
      rd[j]=nd;
      if (nd>bv){bv=nd;bi=t+512*j;}   // indices ascend with j -> first-max kept
    }
#pragma unroll
    for (int off=1;off<64;off<<=1){
      float ov=__shfl_xor(bv,off); int oi=__shfl_xor(bi,off);
      if (ov>bv || (ov==bv && oi<bi)){bv=ov;bi=oi;}   // lowest index wins ties
    }
    if (lane==0){redv[buf][wv]=bv;redi[buf][wv]=bi;}
    __syncthreads();
    float fv=redv[buf][0]; int fi=redi[buf][0];
#pragma unroll
    for (int w=1;w<8;w++){
      float ov=redv[buf][w]; int oi=redi[buf][w];
      if (ov>fv || (ov==fv && oi<fi)){fv=ov;fi=oi;}
    }
    far=fi;
  }
}

// ======================= ball query =======================
__global__ __launch_bounds__(256) void ball_kernel(const float* __restrict__ xyz,
        const float* __restrict__ nxyz, int* __restrict__ grp){
  const int gw   = (blockIdx.x*256 + threadIdx.x) >> 6;  // one wave per group
  const int lane = threadIdx.x & 63;
  if (gw >= NGRP) return;
  const int b = gw / SS;
  const float* xb = xyz + (size_t)b*3*NN;
  const float nx=nxyz[gw*3+0], ny=nxyz[gw*3+1], nz=nxyz[gw*3+2];
  const float sn = __fadd_rn(__fadd_rn(__fmul_rn(nx,nx),__fmul_rn(ny,ny)),__fmul_rn(nz,nz));
  int cnt=0, first=-1;
  int* g = grp + (size_t)gw*KK;
  for (int c=0;c<NN/64 && cnt<KK;c++){
    int i=c*64+lane;
    float x=xb[i], y=xb[NN+i], z=xb[2*NN+i];
    float sxx=__fadd_rn(__fadd_rn(__fmul_rn(x,x),__fmul_rn(y,y)),__fmul_rn(z,z));
    float dot=__fadd_rn(__fadd_rn(__fmul_rn(nx,x),__fmul_rn(ny,y)),__fmul_rn(nz,z));
    float sqr=__fsub_rn(__fadd_rn(sn,sxx),__fmul_rn(2.0f,dot));
    bool m = (sqr <= R2F);
    unsigned long long mask = __ballot(m);
    if (m){
      int pos = cnt + __popcll(mask & ((1ull<<lane)-1ull));
      if (pos < KK) g[pos] = i;
    }
    if (first<0 && mask) first = c*64 + (__ffsll((long long)mask) - 1);
    cnt += __popcll(mask);
  }
  if (cnt < KK && lane >= cnt && lane < KK) g[lane] = first;
}

// ======================= shared device helpers =======================
__device__ __forceinline__ void load_feat(const float* __restrict__ xyz, const float* __restrict__ pts,
        const float* __restrict__ nxyz, const int* __restrict__ grp, int p, float f[6]){
  int gid = p >> 5;          // b*SS+s
  int b   = p >> 14;
  int idx = grp[p];
  const float* xb = xyz + (size_t)b*3*NN;
  const float* pb = pts + (size_t)b*3*NN;
  f[0]=__fsub_rn(xb[idx],      nxyz[gid*3+0]);
  f[1]=__fsub_rn(xb[NN+idx],   nxyz[gid*3+1]);
  f[2]=__fsub_rn(xb[2*NN+idx], nxyz[gid*3+2]);
  f[3]=pb[idx]; f[4]=pb[NN+idx]; f[5]=pb[2*NN+idx];
}

template<int C>
__device__ __forceinline__ void stats_accum(const float z[C], double* __restrict__ part, int slot){
  const int lane = threadIdx.x & 63;
#pragma unroll
  for (int o=0;o<C;o++){
    float s1 = z[o];
    float s2 = __fmul_rn(z[o], z[o]);
#pragma unroll
    for (int off=1;off<64;off<<=1){
      s1 += __shfl_xor(s1,off);
      s2 += __shfl_xor(s2,off);
    }
    if (lane==0){
      atomicAdd(part + o*32 + slot,     (double)s1);
      atomicAdd(part + (C+o)*32 + slot, (double)s2);
    }
  }
}

__global__ void finalize_kernel(const double* __restrict__ part, float* __restrict__ mr, int C){
  int o = threadIdx.x;
  if (o < C){
    double s1=0.0, s2=0.0;
    for (int k=0;k<32;k++){ s1 += part[o*32+k]; s2 += part[(C+o)*32+k]; }
    const double n = (double)NPIX;
    double mean = s1/n;
    double var  = s2/n - mean*mean;
    mr[2*o]   = (float)mean;
    mr[2*o+1] = (float)(1.0/sqrt(var + (double)EPSF));
  }
}

template<int C>
__device__ __forceinline__ void norm_relu(float z[C], const float* __restrict__ mr,
        const float* __restrict__ g, const float* __restrict__ bt){
#pragma unroll
  for (int c=0;c<C;c++){
    float xn = __fmul_rn(__fsub_rn(z[c], mr[2*c]), mr[2*c+1]);
    z[c] = fmaxf(fmaf(xn, g[c], bt[c]), 0.0f);
  }
}

template<int CIN,int COUT>
__device__ __forceinline__ void mmreg(const float* __restrict__ wl, const float* __restrict__ bl,
        const float x[CIN], float y[COUT]){
#pragma unroll
  for (int o=0;o<COUT;o++){
    float a = bl[o];
#pragma unroll
    for (int c=0;c<CIN;c++) a = fmaf(wl[o*CIN+c], x[c], a);
    y[o]=a;
  }
}

// ======================= PATH A (store z) =======================
__global__ __launch_bounds__(256) void l1_store(const float* __restrict__ xyz, const float* __restrict__ pts,
        const float* __restrict__ nxyz, const int* __restrict__ grp,
        const float* __restrict__ w0, const float* __restrict__ b0,
        float* __restrict__ z1, double* __restrict__ part){
  __shared__ float wl[64*6]; __shared__ float bl[64];
  for (int i=threadIdx.x;i<64*6;i+=256) wl[i]=w0[i];
  if (threadIdx.x<64) bl[threadIdx.x]=b0[threadIdx.x];
  __syncthreads();
  int p = blockIdx.x*256 + threadIdx.x;
  float f[6]; load_feat(xyz,pts,nxyz,grp,p,f);
  float z[64];
  mmreg<6,64>(wl, bl, f, z);
#pragma unroll
  for (int o=0;o<64;o++) z1[(size_t)o*NPIX + p] = z[o];
  stats_accum<64>(z, part, (blockIdx.x*4 + (threadIdx.x>>6)) & 31);
}

__global__ __launch_bounds__(256) void l2_store(const float* __restrict__ z1, const float* __restrict__ mr1,
        const float* __restrict__ g0, const float* __restrict__ be0,
        const float* __restrict__ w1, const float* __restrict__ b1,
        float* __restrict__ z2, double* __restrict__ part){
  __shared__ float wl[64*64]; __shared__ float bl[64];
  for (int i=threadIdx.x;i<64*64;i+=256) wl[i]=w1[i];
  if (threadIdx.x<64) bl[threadIdx.x]=b1[threadIdx.x];
  __syncthreads();
  int p = blockIdx.x*256 + threadIdx.x;
  float acc[64];
#pragma unroll
  for (int o=0;o<64;o++) acc[o]=bl[o];
  for (int c=0;c<64;c++){
    float z  = z1[(size_t)c*NPIX + p];
    float xn = __fmul_rn(__fsub_rn(z, mr1[2*c]), mr1[2*c+1]);
    float x  = fmaxf(fmaf(xn, g0[c], be0[c]), 0.0f);
#pragma unroll
    for (int o=0;o<64;o++) acc[o] = fmaf(wl[o*64+c], x, acc[o]);
  }
#pragma unroll
  for (int o=0;o<64;o++) z2[(size_t)o*NPIX+p]=acc[o];
  stats_accum<64>(acc, part, (blockIdx.x*4 + (threadIdx.x>>6)) & 31);
}

__global__ __launch_bounds__(256) void l3_store(const float* __restrict__ z2, const float* __restrict__ mr2,
        const float* __restrict__ g1, const float* __restrict__ be1,
        const float* __restrict__ w2, const float* __restrict__ b2,
        float* __restrict__ z3, double* __restrict__ part){
  __shared__ float wl[128*64]; __shared__ float bl[128];
  for (int i=threadIdx.x;i<128*64;i+=256) wl[i]=w2[i];
  if (threadIdx.x<128) bl[threadIdx.x]=b2[threadIdx.x];
  __syncthreads();
  int p = blockIdx.x*256 + threadIdx.x;
  float acc[128];
#pragma unroll
  for (int o=0;o<128;o++) acc[o]=bl[o];
  for (int c=0;c<64;c++){
    float z  = z2[(size_t)c*NPIX + p];
    float xn = __fmul_rn(__fsub_rn(z, mr2[2*c]), mr2[2*c+1]);
    float x  = fmaxf(fmaf(xn, g1[c], be1[c]), 0.0f);
#pragma unroll
    for (int o=0;o<128;o++) acc[o] = fmaf(wl[o*64+c], x, acc[o]);
  }
#pragma unroll
  for (int o=0;o<128;o++) z3[(size_t)o*NPIX+p]=acc[o];
  stats_accum<128>(acc, part, (blockIdx.x*4 + (threadIdx.x>>6)) & 31);
}

__global__ __launch_bounds__(256) void out_store(const float* __restrict__ z3, const float* __restrict__ mr3,
        const float* __restrict__ g2, const float* __restrict__ be2, float* __restrict__ out1){
  int q = blockIdx.x*256 + threadIdx.x;        // ((b*128+o)*512+s)
  int s = q & (SS-1); int o = (q>>9) & 127; int b = q >> 16;
  size_t base = (size_t)o*NPIX + ((size_t)(b*SS+s))*KK;
  float m = mr3[2*o], r = mr3[2*o+1], gg = g2[o], bt = be2[o];
  float mx = -1e30f;
  const float4* zp = (const float4*)(z3 + base);
#pragma unroll
  for (int j=0;j<8;j++){
    float4 v = zp[j];
    float y0 = fmaxf(fmaf(__fmul_rn(__fsub_rn(v.x,m),r), gg, bt), 0.0f);
    float y1 = fmaxf(fmaf(__fmul_rn(__fsub_rn(v.y,m),r), gg, bt), 0.0f);
    float y2 = fmaxf(fmaf(__fmul_rn(__fsub_rn(v.z,m),r), gg, bt), 0.0f);
    float y3 = fmaxf(fmaf(__fmul_rn(__fsub_rn(v.w,m),r), gg, bt), 0.0f);
    mx = fmaxf(mx, fmaxf(fmaxf(y0,y1), fmaxf(y2,y3)));
  }
  out1[q] = mx;
}

// ======================= PATH B (recompute, tiny ws) =======================
__global__ __launch_bounds__(256) void l1_stats(const float* __restrict__ xyz, const float* __restrict__ pts,
        const float* __restrict__ nxyz, const int* __restrict__ grp,
        const float* __restrict__ w0, const float* __restrict__ b0, double* __restrict__ part){
  __shared__ float wl[64*6]; __shared__ float bl[64];
  for (int i=threadIdx.x;i<64*6;i+=256) wl[i]=w0[i];
  if (threadIdx.x<64) bl[threadIdx.x]=b0[threadIdx.x];
  __syncthreads();
  int p = blockIdx.x*256 + threadIdx.x;
  float f[6]; load_feat(xyz,pts,nxyz,grp,p,f);
  float z[64];
  mmreg<6,64>(wl, bl, f, z);
  stats_accum<64>(z, part, (blockIdx.x*4 + (threadIdx.x>>6)) & 31);
}

__global__ __launch_bounds__(256) void l2_stats(const float* __restrict__ xyz, const float* __restrict__ pts,
        const float* __restrict__ nxyz, const int* __restrict__ grp,
        const float* __restrict__ w0, const float* __restrict__ b0,
        const float* __restrict__ mr1, const float* __restrict__ g0, const float* __restrict__ be0,
        const float* __restrict__ w1, const float* __restrict__ b1, double* __restrict__ part){
  __shared__ float wl0[64*6]; __shared__ float bl0[64];
  __shared__ float wl1[64*64]; __shared__ float bl1[64];
  for (int i=threadIdx.x;i<64*6;i+=256)  wl0[i]=w0[i];
  for (int i=threadIdx.x;i<64*64;i+=256) wl1[i]=w1[i];
  if (threadIdx.x<64){ bl0[threadIdx.x]=b0[threadIdx.x]; bl1[threadIdx.x]=b1[threadIdx.x]; }
  __syncthreads();
  int p = blockIdx.x*256 + threadIdx.x;
  float f[6]; load_feat(xyz,pts,nxyz,grp,p,f);
  float z1[64]; mmreg<6,64>(wl0, bl0, f, z1);
  norm_relu<64>(z1, mr1, g0, be0);
  float z2[64]; mmreg<64,64>(wl1, bl1, z1, z2);
  stats_accum<64>(z2, part, (blockIdx.x*4 + (threadIdx.x>>6)) & 31);
}

__global__ __launch_bounds__(256) void l3_stats(const float* __restrict__ xyz, const float* __restrict__ pts,
        const float* __restrict__ nxyz, const int* __restrict__ grp,
        const float* __restrict__ w0, const float* __restrict__ b0,
        const float* __restrict__ mr1, const float* __restrict__ g0, const float* __restrict__ be0,
        const float* __restrict__ w1, const float* __restrict__ b1,
        const float* __restrict__ mr2, const float* __restrict__ g1, const float* __restrict__ be1,
        const float* __restrict__ w2, const float* __restrict__ b2, double* __restrict__ part){
  __shared__ float wl0[64*6]; __shared__ float bl0[64];
  __shared__ float wl1[64*64]; __shared__ float bl1[64];
  __shared__ float wl2[128*64]; __shared__ float bl2[128];
  for (int i=threadIdx.x;i<64*6;i+=256)   wl0[i]=w0[i];
  for (int i=threadIdx.x;i<64*64;i+=256)  wl1[i]=w1[i];
  for (int i=threadIdx.x;i<128*64;i+=256) wl2[i]=w2[i];
  if (threadIdx.x<64){ bl0[threadIdx.x]=b0[threadIdx.x]; bl1[threadIdx.x]=b1[threadIdx.x]; }
  if (threadIdx.x<128) bl2[threadIdx.x]=b2[threadIdx.x];
  __syncthreads();
  int p = blockIdx.x*256 + threadIdx.x;
  float f[6]; load_feat(xyz,pts,nxyz,grp,p,f);
  float z1[64]; mmreg<6,64>(wl0, bl0, f, z1);
  norm_relu<64>(z1, mr1, g0, be0);
  float z2[64]; mmreg<64,64>(wl1, bl1, z1, z2);
  norm_relu<64>(z2, mr2, g1, be1);
  float z3[128]; mmreg<64,128>(wl2, bl2, z2, z3);
  stats_accum<128>(z3, part, (blockIdx.x*4 + (threadIdx.x>>6)) & 31);
}

__global__ __launch_bounds__(256) void out_rec(const float* __restrict__ xyz, const float* __restrict__ pts,
        const float* __restrict__ nxyz, const int* __restrict__ grp,
        const float* __restrict__ w0, const float* __restrict__ b0,
        const float* __restrict__ mr1, const float* __restrict__ g0, const float* __restrict__ be0,
        const float* __restrict__ w1, const float* __restrict__ b1,
        const float* __restrict__ mr2, const float* __restrict__ g1, const float* __restrict__ be1,
        const float* __restrict__ w2, const float* __restrict__ b2,
        const float* __restrict__ mr3, const float* __restrict__ g2, const float* __restrict__ be2,
        float* __restrict__ out1){
  __shared__ float wl0[64*6]; __shared__ float bl0[64];
  __shared__ float wl1[64*64]; __shared__ float bl1[64];
  __shared__ float wl2[128*64]; __shared__ float bl2[128];
  for (int i=threadIdx.x;i<64*6;i+=256)   wl0[i]=w0[i];
  for (int i=threadIdx.x;i<64*64;i+=256)  wl1[i]=w1[i];
  for (int i=threadIdx.x;i<128*64;i+=256) wl2[i]=w2[i];
  if (threadIdx.x<64){ bl0[threadIdx.x]=b0[threadIdx.x]; bl1[threadIdx.x]=b1[threadIdx.x]; }
  if (threadIdx.x<128) bl2[threadIdx.x]=b2[threadIdx.x];
  __syncthreads();
  int p = blockIdx.x*256 + threadIdx.x;
  float f[6]; load_feat(xyz,pts,nxyz,grp,p,f);
  float z1[64]; mmreg<6,64>(wl0, bl0, f, z1);
  norm_relu<64>(z1, mr1, g0, be0);
  float z2[64]; mmreg<64,64>(wl1, bl1, z1, z2);
  norm_relu<64>(z2, mr2, g1, be1);
  float z3[128]; mmreg<64,128>(wl2, bl2, z2, z3);
  norm_relu<128>(z3, mr3, g2, be2);
  const int lane = threadIdx.x & 63;
#pragma unroll
  for (int o=0;o<128;o++){
    float v = z3[o];
#pragma unroll
    for (int off=1;off<32;off<<=1) v = fmaxf(v, __shfl_xor(v, off));
    z3[o]=v;
  }
  if ((lane & 31) == 0){
    int gid = p >> 5;                 // b*SS+s
    int b = gid >> 9, s = gid & (SS-1);
#pragma unroll
    for (int o=0;o<128;o++) out1[((size_t)(b*128+o))*SS + s] = z3[o];
  }
}

// ======================= launch =======================
extern "C" void kernel_launch(void* const* d_in, const int* in_sizes, int n_in,
                              void* d_out, int out_size, void* d_ws, size_t ws_size,
                              hipStream_t stream){
  const float* xyz = (const float*)d_in[0];
  const float* pts = (const float*)d_in[1];
  const float* w0  = (const float*)d_in[2];  const float* b0  = (const float*)d_in[3];
  const float* g0  = (const float*)d_in[4];  const float* be0 = (const float*)d_in[5];
  const float* w1  = (const float*)d_in[6];  const float* b1  = (const float*)d_in[7];
  const float* g1  = (const float*)d_in[8];  const float* be1 = (const float*)d_in[9];
  const float* w2  = (const float*)d_in[10]; const float* b2  = (const float*)d_in[11];
  const float* g2  = (const float*)d_in[12]; const float* be2 = (const float*)d_in[13];

  float* out  = (float*)d_out;
  float* out1 = out + BB*3*SS;
  char*  ws   = (char*)d_ws;

  float*  nxyz = (float*)(ws + OFF_NXYZ);
  int*    grp  = (int*)  (ws + OFF_GRP);
  double* p1   = (double*)(ws + OFF_P1);
  double* p2   = (double*)(ws + OFF_P2);
  double* p3   = (double*)(ws + OFF_P3);
  float*  mr1  = (float*)(ws + OFF_MR1);
  float*  mr2  = (float*)(ws + OFF_MR2);
  float*  mr3  = (float*)(ws + OFF_MR3);
  float*  z1   = (float*)(ws + OFF_Z);
  float*  z2   = z1 + (size_t)64*NPIX;
  float*  z3   = z2 + (size_t)64*NPIX;

  const bool big = (ws_size >= NEED_WS);

  hipMemsetAsync(ws + OFF_P1, 0, 32768+32768+65536, stream);

  fps_kernel <<<BB, 512, 0, stream>>>(xyz, out, nxyz);
  ball_kernel<<<NGRP*64/256, 256, 0, stream>>>(xyz, nxyz, grp);

  if (big){
    l1_store<<<NPIX/256, 256, 0, stream>>>(xyz, pts, nxyz, grp, w0, b0, z1, p1);
    finalize_kernel<<<1,128,0,stream>>>(p1, mr1, 64);
    l2_store<<<NPIX/256, 256, 0, stream>>>(z1, mr1, g0, be0, w1, b1, z2, p2);
    finalize_kernel<<<1,128,0,stream>>>(p2, mr2, 64);
    l3_store<<<NPIX/256, 256, 0, stream>>>(z2, mr2, g1, be1, w2, b2, z3, p3);
    finalize_kernel<<<1,128,0,stream>>>(p3, mr3, 128);
    out_store<<<(BB*128*SS)/256, 256, 0, stream>>>(z3, mr3, g2, be2, out1);
  } else {
    l1_stats<<<NPIX/256, 256, 0, stream>>>(xyz, pts, nxyz, grp, w0, b0, p1);
    finalize_kernel<<<1,128,0,stream>>>(p1, mr1, 64);
    l2_stats<<<NPIX/256, 256, 0, stream>>>(xyz, pts, nxyz, grp, w0, b0, mr1, g0, be0, w1, b1, p2);
    finalize_kernel<<<1,128,0,stream>>>(p2, mr2, 64);
    l3_stats<<<NPIX/256, 256, 0, stream>>>(xyz, pts, nxyz, grp, w0, b0, mr1, g0, be0, w1, b1,
                                           mr2, g1, be1, w2, b2, p3);
    finalize_kernel<<<1,128,0,stream>>>(p3, mr3, 128);
    out_rec<<<NPIX/256, 256, 0, stream>>>(xyz, pts, nxyz, grp, w0, b0, mr1, g0, be0, w1, b1,
                                          mr2, g1, be1, w2, b2, mr3, g2, be2, out1);
  }
}

// Round 3
// 1363.992 us; speedup vs baseline: 7.4229x; 7.4229x over previous
//
#include <hip/hip_runtime.h>
#include <math.h>

#define BB 16
#define NN 4096
#define SS 512
#define KK 32
#define NPIX (BB*SS*KK)          /* 262144 pixels (b,s,k) */
#define NGRP (BB*SS)             /* 8192 groups */

static constexpr float R2F  = (float)0.16000000000000003;  // RADIUS**2 as f32
static constexpr float EPSF = 1e-5f;

// ---------------- workspace layout (bytes) ----------------
constexpr size_t OFF_NXYZ = 0;                     // B*S*3 f32  = 98304
constexpr size_t OFF_GRP  = 98304;                 // B*S*NS i32 = 1048576
constexpr size_t OFF_P1   = 98304 + 1048576;       // 2*64*32 f64  = 32768
constexpr size_t OFF_P2   = OFF_P1 + 32768;
constexpr size_t OFF_P3   = OFF_P2 + 32768;        // 2*128*32 f64 = 65536
constexpr size_t OFF_MR1  = OFF_P3 + 65536;        // 64*2 f32
constexpr size_t OFF_MR2  = OFF_MR1 + 512;
constexpr size_t OFF_MR3  = OFF_MR2 + 512;         // 128*2 f32

// ======================= FPS (unchanged, passing) =======================
__global__ __launch_bounds__(512) void fps_kernel(const float* __restrict__ xyz,
        float* __restrict__ out0, float* __restrict__ nxyz){
  const int b = blockIdx.x;
  const float* xb = xyz + (size_t)b*3*NN;
  __shared__ float sx[NN], sy[NN], sz[NN];
  __shared__ float redv[2][8];
  __shared__ int   redi[2][8];
  const int t = threadIdx.x;
  float rx[8], ry[8], rz[8], rd[8];
#pragma unroll
  for (int j=0;j<8;j++){
    int i = t + 512*j;
    float x = xb[i], y = xb[NN+i], z = xb[2*NN+i];
    rx[j]=x; ry[j]=y; rz[j]=z;
    sx[i]=x; sy[i]=y; sz[i]=z;
    rd[j]=1e10f;
  }
  __syncthreads();
  int far = 0;
  const int lane = t & 63, wv = t >> 6;
  for (int s=0;s<SS;s++){
    const int buf = s & 1;
    float cx = sx[far], cy = sy[far], cz = sz[far];
    if (t==0){
      nxyz[(b*SS+s)*3+0]=cx; nxyz[(b*SS+s)*3+1]=cy; nxyz[(b*SS+s)*3+2]=cz;
      out0[(b*3+0)*SS+s]=cx; out0[(b*3+1)*SS+s]=cy; out0[(b*3+2)*SS+s]=cz;
    }
    float bv=-1.0f; int bi=0;
#pragma unroll
    for (int j=0;j<8;j++){
      float dx=__fsub_rn(rx[j],cx), dy=__fsub_rn(ry[j],cy), dz=__fsub_rn(rz[j],cz);
      float d2=__fadd_rn(__fadd_rn(__fmul_rn(dx,dx),__fmul_rn(dy,dy)),__fmul_rn(dz,dz));
      float nd=fminf(rd[j],d2);
      rd[j]=nd;
      if (nd>bv){bv=nd;bi=t+512*j;}
    }
#pragma unroll
    for (int off=1;off<64;off<<=1){
      float ov=__shfl_xor(bv,off); int oi=__shfl_xor(bi,off);
      if (ov>bv || (ov==bv && oi<bi)){bv=ov;bi=oi;}
    }
    if (lane==0){redv[buf][wv]=bv;redi[buf][wv]=bi;}
    __syncthreads();
    float fv=redv[buf][0]; int fi=redi[buf][0];
#pragma unroll
    for (int w=1;w<8;w++){
      float ov=redv[buf][w]; int oi=redi[buf][w];
      if (ov>fv || (ov==fv && oi<fi)){fv=ov;fi=oi;}
    }
    far=fi;
  }
}

// ======================= ball query (unchanged, passing) =======================
__global__ __launch_bounds__(256) void ball_kernel(const float* __restrict__ xyz,
        const float* __restrict__ nxyz, int* __restrict__ grp){
  const int gw   = (blockIdx.x*256 + threadIdx.x) >> 6;
  const int lane = threadIdx.x & 63;
  if (gw >= NGRP) return;
  const int b = gw / SS;
  const float* xb = xyz + (size_t)b*3*NN;
  const float nx=nxyz[gw*3+0], ny=nxyz[gw*3+1], nz=nxyz[gw*3+2];
  const float sn = __fadd_rn(__fadd_rn(__fmul_rn(nx,nx),__fmul_rn(ny,ny)),__fmul_rn(nz,nz));
  int cnt=0, first=-1;
  int* g = grp + (size_t)gw*KK;
  for (int c=0;c<NN/64 && cnt<KK;c++){
    int i=c*64+lane;
    float x=xb[i], y=xb[NN+i], z=xb[2*NN+i];
    float sxx=__fadd_rn(__fadd_rn(__fmul_rn(x,x),__fmul_rn(y,y)),__fmul_rn(z,z));
    float dot=__fadd_rn(__fadd_rn(__fmul_rn(nx,x),__fmul_rn(ny,y)),__fmul_rn(nz,z));
    float sqr=__fsub_rn(__fadd_rn(sn,sxx),__fmul_rn(2.0f,dot));
    bool m = (sqr <= R2F);
    unsigned long long mask = __ballot(m);
    if (m){
      int pos = cnt + __popcll(mask & ((1ull<<lane)-1ull));
      if (pos < KK) g[pos] = i;
    }
    if (first<0 && mask) first = c*64 + (__ffsll((long long)mask) - 1);
    cnt += __popcll(mask);
  }
  if (cnt < KK && lane >= cnt && lane < KK) g[lane] = first;
}

// ======================= finalize (unchanged) =======================
__global__ void finalize_kernel(const double* __restrict__ part, float* __restrict__ mr, int C){
  int o = threadIdx.x;
  if (o < C){
    double s1=0.0, s2=0.0;
    for (int k=0;k<32;k++){ s1 += part[o*32+k]; s2 += part[(C+o)*32+k]; }
    const double n = (double)NPIX;
    double mean = s1/n;
    double var  = s2/n - mean*mean;
    mr[2*o]   = (float)mean;
    mr[2*o+1] = (float)(1.0/sqrt(var + (double)EPSF));
  }
}

// ======================= tiled MLP chain =======================
// Block: 256 threads (ty=t>>4 in [0,16): 4 pixels each; tx=t&15: 4 (or 8) chans).
// 64 pixels/block, 4096 blocks. Weights transposed in LDS (w_t[k][ch]),
// activations ping-pong through one LDS buffer x[ch][px], stride 68 (16B-aligned,
// <=2-way banks). Per-thread acc tile keeps VGPRs low -> no scratch spills
// (round-2 profile: spills cost 13 GB of traffic per l3 dispatch).
// LDS float offsets:
constexpr int XIN = 0;          // 6*68   = 408
constexpr int W0F = 408;        // 6*64   = 384
constexpr int B0F = 792;        // 64
constexpr int W1F = 856;        // 64*64  = 4096
constexpr int B1F = 4952;       // 64
constexpr int XBF = 5016;       // 64*68  = 4352
constexpr int SRF = 9368;       // 256  (f32 stats red, or u32 maxpool)
constexpr int W2F = 9624;       // 64*128 = 8192
constexpr int B2F = 17816;      // 128
constexpr int SM_SMALL = 9624;  // stages 1,2 (38.5 KB)
constexpr int SM_BIG   = 17944; // stages 3,4 (71.8 KB -> 2 blocks/CU)

template<int STAGE>
__global__ __launch_bounds__(256,2) void mlp_kernel(
    const float* __restrict__ xyz, const float* __restrict__ pts,
    const float* __restrict__ nxyz, const int* __restrict__ grp,
    const float* __restrict__ w0, const float* __restrict__ b0,
    const float* __restrict__ mr1, const float* __restrict__ g0, const float* __restrict__ be0,
    const float* __restrict__ w1, const float* __restrict__ b1,
    const float* __restrict__ mr2, const float* __restrict__ g1, const float* __restrict__ be1,
    const float* __restrict__ w2, const float* __restrict__ b2,
    const float* __restrict__ mr3, const float* __restrict__ g2, const float* __restrict__ be2,
    double* __restrict__ part, float* __restrict__ out1)
{
  __shared__ float sm[(STAGE>=3)? SM_BIG : SM_SMALL];
  const int t   = threadIdx.x;
  const int blk = blockIdx.x;
  const int tx  = t & 15, ty = t >> 4;
  const int p0  = blk*64;
  const int slot = blk & 31;

  // init reduction / maxpool slot
  sm[SRF + t] = 0.0f;   // 0.0f bit pattern == 0u, valid for both uses

  // ---- stage weights (transposed) + biases + features ----
  for (int i=t;i<384;i+=256){ int o=i/6, c=i-o*6; sm[W0F + c*64 + o] = w0[i]; }
  if (t<64) sm[B0F+t] = b0[t];
  if constexpr (STAGE>=2){
    for (int i=t;i<4096;i+=256){ int o=i&63, c=i>>6; sm[W1F + c*64 + o] = w1[o*64+c]; }
    if (t<64) sm[B1F+t] = b1[t];
  }
  if constexpr (STAGE>=3){
    for (int i=t;i<8192;i+=256){ int o=i&127, c=i>>7; sm[W2F + c*128 + o] = w2[o*64+c]; }
    if (t<128) sm[B2F+t] = b2[t];
  }
  for (int i=t;i<384;i+=256){
    int c=i>>6, px=i&63, p=p0+px, gid=p>>5, bb=p>>14;
    int idx = grp[p];
    float v;
    if (c<3) v = __fsub_rn(xyz[(size_t)bb*3*NN + c*NN + idx], nxyz[gid*3+c]);
    else     v = pts[(size_t)bb*3*NN + (c-3)*NN + idx];
    sm[XIN + c*68 + px] = v;
  }
  __syncthreads();

  // ---- layer 1: 6 -> 64 ----
  float z[4][4];
#pragma unroll
  for (int i=0;i<4;i++)
#pragma unroll
    for (int j=0;j<4;j++) z[i][j]=0.0f;
#pragma unroll
  for (int k=0;k<6;k++){
    float4 xv = *(const float4*)&sm[XIN + k*68 + ty*4];
    float4 wv = *(const float4*)&sm[W0F + k*64 + tx*4];
    const float xs[4]={xv.x,xv.y,xv.z,xv.w};
    const float wsv[4]={wv.x,wv.y,wv.z,wv.w};
#pragma unroll
    for (int i=0;i<4;i++)
#pragma unroll
      for (int j=0;j<4;j++) z[i][j] = fmaf(xs[i], wsv[j], z[i][j]);
  }
#pragma unroll
  for (int i=0;i<4;i++)
#pragma unroll
    for (int j=0;j<4;j++) z[i][j] = __fadd_rn(z[i][j], sm[B0F + tx*4 + j]);

  if constexpr (STAGE==1){
#pragma unroll
    for (int j=0;j<4;j++){
      float s1=0.0f, s2=0.0f;
#pragma unroll
      for (int i=0;i<4;i++){ s1 = __fadd_rn(s1, z[i][j]); s2 = fmaf(z[i][j], z[i][j], s2); }
      atomicAdd(&sm[SRF + (tx*4+j)*2    ], s1);
      atomicAdd(&sm[SRF + (tx*4+j)*2 + 1], s2);
    }
    __syncthreads();
    if (t<128){ int ch=t>>1, m=t&1;
      atomicAdd(part + (size_t)((m? 64+ch : ch)*32 + slot), (double)sm[SRF+t]);
    }
    return;
  }

  if constexpr (STAGE>=2){
    // norm+relu(mr1) -> xbuf
#pragma unroll
    for (int j=0;j<4;j++){
      int ch = tx*4+j;
      float m=mr1[2*ch], r=mr1[2*ch+1], gg=g0[ch], bt=be0[ch];
      float4 o;
      o.x = fmaxf(fmaf(__fmul_rn(__fsub_rn(z[0][j],m),r), gg, bt), 0.0f);
      o.y = fmaxf(fmaf(__fmul_rn(__fsub_rn(z[1][j],m),r), gg, bt), 0.0f);
      o.z = fmaxf(fmaf(__fmul_rn(__fsub_rn(z[2][j],m),r), gg, bt), 0.0f);
      o.w = fmaxf(fmaf(__fmul_rn(__fsub_rn(z[3][j],m),r), gg, bt), 0.0f);
      *(float4*)&sm[XBF + ch*68 + ty*4] = o;
    }
    __syncthreads();

    // ---- layer 2: 64 -> 64 ----
#pragma unroll
    for (int i=0;i<4;i++)
#pragma unroll
      for (int j=0;j<4;j++) z[i][j]=0.0f;
#pragma unroll 8
    for (int k=0;k<64;k++){
      float4 xv = *(const float4*)&sm[XBF + k*68 + ty*4];
      float4 wv = *(const float4*)&sm[W1F + k*64 + tx*4];
      const float xs[4]={xv.x,xv.y,xv.z,xv.w};
      const float wsv[4]={wv.x,wv.y,wv.z,wv.w};
#pragma unroll
      for (int i=0;i<4;i++)
#pragma unroll
        for (int j=0;j<4;j++) z[i][j] = fmaf(xs[i], wsv[j], z[i][j]);
    }
#pragma unroll
    for (int i=0;i<4;i++)
#pragma unroll
      for (int j=0;j<4;j++) z[i][j] = __fadd_rn(z[i][j], sm[B1F + tx*4 + j]);

    if constexpr (STAGE==2){
#pragma unroll
      for (int j=0;j<4;j++){
        float s1=0.0f, s2=0.0f;
#pragma unroll
        for (int i=0;i<4;i++){ s1 = __fadd_rn(s1, z[i][j]); s2 = fmaf(z[i][j], z[i][j], s2); }
        atomicAdd(&sm[SRF + (tx*4+j)*2    ], s1);
        atomicAdd(&sm[SRF + (tx*4+j)*2 + 1], s2);
      }
      __syncthreads();
      if (t<128){ int ch=t>>1, m=t&1;
        atomicAdd(part + (size_t)((m? 64+ch : ch)*32 + slot), (double)sm[SRF+t]);
      }
      return;
    }
  }

  if constexpr (STAGE>=3){
    // all reads of x1 done -> safe to overwrite xbuf with x2
    __syncthreads();
#pragma unroll
    for (int j=0;j<4;j++){
      int ch = tx*4+j;
      float m=mr2[2*ch], r=mr2[2*ch+1], gg=g1[ch], bt=be1[ch];
      float4 o;
      o.x = fmaxf(fmaf(__fmul_rn(__fsub_rn(z[0][j],m),r), gg, bt), 0.0f);
      o.y = fmaxf(fmaf(__fmul_rn(__fsub_rn(z[1][j],m),r), gg, bt), 0.0f);
      o.z = fmaxf(fmaf(__fmul_rn(__fsub_rn(z[2][j],m),r), gg, bt), 0.0f);
      o.w = fmaxf(fmaf(__fmul_rn(__fsub_rn(z[3][j],m),r), gg, bt), 0.0f);
      *(float4*)&sm[XBF + ch*68 + ty*4] = o;
    }
    __syncthreads();

    // ---- layer 3: 64 -> 128 (thread owns 8 chans: tx*4.. and 64+tx*4..) ----
    float a3[4][8];
#pragma unroll
    for (int i=0;i<4;i++)
#pragma unroll
      for (int j=0;j<8;j++) a3[i][j]=0.0f;
#pragma unroll 4
    for (int k=0;k<64;k++){
      float4 xv  = *(const float4*)&sm[XBF + k*68  + ty*4];
      float4 wv0 = *(const float4*)&sm[W2F + k*128 + tx*4];
      float4 wv1 = *(const float4*)&sm[W2F + k*128 + 64 + tx*4];
      const float xs[4]={xv.x,xv.y,xv.z,xv.w};
      const float wsv[8]={wv0.x,wv0.y,wv0.z,wv0.w, wv1.x,wv1.y,wv1.z,wv1.w};
#pragma unroll
      for (int i=0;i<4;i++)
#pragma unroll
        for (int j=0;j<8;j++) a3[i][j] = fmaf(xs[i], wsv[j], a3[i][j]);
    }
#pragma unroll
    for (int i=0;i<4;i++)
#pragma unroll
      for (int j=0;j<8;j++){
        int ch = (j<4)? (tx*4+j) : (64+tx*4+(j-4));
        a3[i][j] = __fadd_rn(a3[i][j], sm[B2F + ch]);
      }

    if constexpr (STAGE==3){
#pragma unroll
      for (int j=0;j<8;j++){
        int ch = (j<4)? (tx*4+j) : (64+tx*4+(j-4));
        float s1=0.0f, s2=0.0f;
#pragma unroll
        for (int i=0;i<4;i++){ s1 = __fadd_rn(s1, a3[i][j]); s2 = fmaf(a3[i][j], a3[i][j], s2); }
        atomicAdd(&sm[SRF + ch*2    ], s1);
        atomicAdd(&sm[SRF + ch*2 + 1], s2);
      }
      __syncthreads();
      { int ch=t>>1, m=t&1;
        atomicAdd(part + (size_t)((m? 128+ch : ch)*32 + slot), (double)sm[SRF+t]);
      }
      return;
    }

    if constexpr (STAGE==4){
      const int grp_l = ty>>3;   // which of the 2 groups this thread's 4 px lie in
      unsigned* omax = (unsigned*)sm;
#pragma unroll
      for (int j=0;j<8;j++){
        int ch = (j<4)? (tx*4+j) : (64+tx*4+(j-4));
        float m=mr3[2*ch], r=mr3[2*ch+1], gg=g2[ch], bt=be2[ch];
        float vmax=0.0f;
#pragma unroll
        for (int i=0;i<4;i++){
          float v = fmaxf(fmaf(__fmul_rn(__fsub_rn(a3[i][j],m),r), gg, bt), 0.0f);
          vmax = fmaxf(vmax, v);
        }
        atomicMax(&omax[SRF + grp_l*128 + ch], __float_as_uint(vmax));
      }
      __syncthreads();
      { int g = t>>7, o = t&127;
        int gid = blk*2 + g, bb = gid>>9, s = gid&511;
        out1[((size_t)(bb*128+o))*512 + s] = __uint_as_float(omax[SRF + t]);
      }
    }
  }
}

// ======================= launch =======================
extern "C" void kernel_launch(void* const* d_in, const int* in_sizes, int n_in,
                              void* d_out, int out_size, void* d_ws, size_t ws_size,
                              hipStream_t stream){
  const float* xyz = (const float*)d_in[0];
  const float* pts = (const float*)d_in[1];
  const float* w0  = (const float*)d_in[2];  const float* b0  = (const float*)d_in[3];
  const float* g0  = (const float*)d_in[4];  const float* be0 = (const float*)d_in[5];
  const float* w1  = (const float*)d_in[6];  const float* b1  = (const float*)d_in[7];
  const float* g1  = (const float*)d_in[8];  const float* be1 = (const float*)d_in[9];
  const float* w2  = (const float*)d_in[10]; const float* b2  = (const float*)d_in[11];
  const float* g2  = (const float*)d_in[12]; const float* be2 = (const float*)d_in[13];

  float* out  = (float*)d_out;
  float* out1 = out + BB*3*SS;
  char*  ws   = (char*)d_ws;

  float*  nxyz = (float*)(ws + OFF_NXYZ);
  int*    grp  = (int*)  (ws + OFF_GRP);
  double* p1   = (double*)(ws + OFF_P1);
  double* p2   = (double*)(ws + OFF_P2);
  double* p3   = (double*)(ws + OFF_P3);
  float*  mr1  = (float*)(ws + OFF_MR1);
  float*  mr2  = (float*)(ws + OFF_MR2);
  float*  mr3  = (float*)(ws + OFF_MR3);

  hipMemsetAsync(ws + OFF_P1, 0, 32768+32768+65536, stream);

  fps_kernel <<<BB, 512, 0, stream>>>(xyz, out, nxyz);
  ball_kernel<<<NGRP*64/256, 256, 0, stream>>>(xyz, nxyz, grp);

#define MLP_ARGS xyz, pts, nxyz, grp, w0, b0, mr1, g0, be0, w1, b1, mr2, g1, be1, w2, b2, mr3, g2, be2
  mlp_kernel<1><<<NPIX/64, 256, 0, stream>>>(MLP_ARGS, p1, out1);
  finalize_kernel<<<1,128,0,stream>>>(p1, mr1, 64);
  mlp_kernel<2><<<NPIX/64, 256, 0, stream>>>(MLP_ARGS, p2, out1);
  finalize_kernel<<<1,128,0,stream>>>(p2, mr2, 64);
  mlp_kernel<3><<<NPIX/64, 256, 0, stream>>>(MLP_ARGS, p3, out1);
  finalize_kernel<<<1,128,0,stream>>>(p3, mr3, 128);
  mlp_kernel<4><<<NPIX/64, 256, 0, stream>>>(MLP_ARGS, p3, out1);
#undef MLP_ARGS
}

// Round 5
// 926.430 us; speedup vs baseline: 10.9288x; 1.4723x over previous
//
#include <hip/hip_runtime.h>
#include <math.h>

#define BB 16
#define NN 4096
#define SS 512
#define KK 32
#define NPIX (BB*SS*KK)          /* 262144 pixels (b,s,k) */
#define NGRP (BB*SS)             /* 8192 groups */

static constexpr float R2F  = (float)0.16000000000000003;  // RADIUS**2 as f32
static constexpr float EPSF = 1e-5f;

// ---------------- workspace layout (bytes) ----------------
constexpr size_t OFF_NXYZ = 0;                     // B*S*3 f32  = 98304
constexpr size_t OFF_GRP  = 98304;                 // B*S*NS i32 = 1048576
constexpr size_t OFF_P1   = 98304 + 1048576;       // 2*64*32 f64  = 32768
constexpr size_t OFF_P2   = OFF_P1 + 32768;
constexpr size_t OFF_P3   = OFF_P2 + 32768;        // 2*128*32 f64 = 65536
constexpr size_t OFF_MR1  = OFF_P3 + 65536;        // 64*2 f32
constexpr size_t OFF_MR2  = OFF_MR1 + 512;
constexpr size_t OFF_MR3  = OFF_MR2 + 512;         // 128*2 f32
constexpr size_t OFF_Z3   = 2*1024*1024;
constexpr size_t Z3SZ     = (size_t)NPIX*128*4;    // 134217728

// ======================= FPS =======================
// 512 threads, 8 pts/thread. Critical-path fixes vs round 3:
//  - NO global stores inside the step loop (they forced a vmcnt(0) drain at
//    every __syncthreads); selection history goes to LDS, written out after.
//  - (dist,idx) packed into u64 (dist f32 bits hi, ~idx lo) -> reduce levels
//    are 2 shfl + 1 u64 cmp; exact lowest-index tie-break preserved.
//  - points interleaved as float4 in LDS -> 1 ds_read_b128 centroid fetch.
__global__ __launch_bounds__(512) void fps_kernel(const float* __restrict__ xyz,
        float* __restrict__ out0, float* __restrict__ nxyz){
  const int b = blockIdx.x;
  const float* xb = xyz + (size_t)b*3*NN;
  __shared__ float4 pt4[NN];                       // 64 KB
  __shared__ unsigned long long redp[2][8];
  __shared__ int hist[SS];
  const int t = threadIdx.x;
  float rx[8], ry[8], rz[8], rd[8];
#pragma unroll
  for (int j=0;j<8;j++){
    int i = t + 512*j;
    float x = xb[i], y = xb[NN+i], z = xb[2*NN+i];
    rx[j]=x; ry[j]=y; rz[j]=z;
    pt4[i] = make_float4(x,y,z,0.0f);
    rd[j]=1e10f;
  }
  __syncthreads();
  int far = 0;
  const int lane = t & 63, wv = t >> 6;
  for (int s=0;s<SS;s++){
    const int buf = s & 1;
    float4 c = pt4[far];
    if (t==0) hist[s] = far;
    float bv=-1.0f; int bi=0;
#pragma unroll
    for (int j=0;j<8;j++){
      float dx=__fsub_rn(rx[j],c.x), dy=__fsub_rn(ry[j],c.y), dz=__fsub_rn(rz[j],c.z);
      float d2=__fadd_rn(__fadd_rn(__fmul_rn(dx,dx),__fmul_rn(dy,dy)),__fmul_rn(dz,dz));
      float nd=fminf(rd[j],d2);
      rd[j]=nd;
      if (nd>bv){bv=nd;bi=t+512*j;}   // indices ascend with j -> first-max kept
    }
    // pack: dist (>=0, bits monotone) hi, ~idx lo (ties -> lowest idx wins max)
    unsigned long long pk = ((unsigned long long)__float_as_uint(bv) << 32)
                          | (unsigned)(~(unsigned)bi);
#pragma unroll
    for (int off=1;off<64;off<<=1){
      unsigned long long o = __shfl_xor(pk, off);
      pk = (o > pk) ? o : pk;
    }
    if (lane==0) redp[buf][wv]=pk;
    __syncthreads();   // only lgkm traffic outstanding -> cheap drain
    unsigned long long m = redp[buf][0];
#pragma unroll
    for (int w=1;w<8;w++){ unsigned long long o=redp[buf][w]; if (o>m) m=o; }
    far = (int)(~(unsigned)(m & 0xFFFFFFFFull));
    // no WAR barrier: redp[buf] rewritten at step s+2, after step s+1's barrier
  }
  __syncthreads();
  // cooperative writeout (once)
  {
    int idx = hist[t];           // t in [0,512) == SS
    float4 c = pt4[idx];
    int gid = b*SS + t;
    nxyz[gid*3+0]=c.x; nxyz[gid*3+1]=c.y; nxyz[gid*3+2]=c.z;
    out0[(b*3+0)*SS+t]=c.x; out0[(b*3+1)*SS+t]=c.y; out0[(b*3+2)*SS+t]=c.z;
  }
}

// ======================= ball query (unchanged, passing) =======================
__global__ __launch_bounds__(256) void ball_kernel(const float* __restrict__ xyz,
        const float* __restrict__ nxyz, int* __restrict__ grp){
  const int gw   = (blockIdx.x*256 + threadIdx.x) >> 6;
  const int lane = threadIdx.x & 63;
  if (gw >= NGRP) return;
  const int b = gw / SS;
  const float* xb = xyz + (size_t)b*3*NN;
  const float nx=nxyz[gw*3+0], ny=nxyz[gw*3+1], nz=nxyz[gw*3+2];
  const float sn = __fadd_rn(__fadd_rn(__fmul_rn(nx,nx),__fmul_rn(ny,ny)),__fmul_rn(nz,nz));
  int cnt=0, first=-1;
  int* g = grp + (size_t)gw*KK;
  for (int c=0;c<NN/64 && cnt<KK;c++){
    int i=c*64+lane;
    float x=xb[i], y=xb[NN+i], z=xb[2*NN+i];
    float sxx=__fadd_rn(__fadd_rn(__fmul_rn(x,x),__fmul_rn(y,y)),__fmul_rn(z,z));
    float dot=__fadd_rn(__fadd_rn(__fmul_rn(nx,x),__fmul_rn(ny,y)),__fmul_rn(nz,z));
    float sqr=__fsub_rn(__fadd_rn(sn,sxx),__fmul_rn(2.0f,dot));
    bool m = (sqr <= R2F);
    unsigned long long mask = __ballot(m);
    if (m){
      int pos = cnt + __popcll(mask & ((1ull<<lane)-1ull));
      if (pos < KK) g[pos] = i;
    }
    if (first<0 && mask) first = c*64 + (__ffsll((long long)mask) - 1);
    cnt += __popcll(mask);
  }
  if (cnt < KK && lane >= cnt && lane < KK) g[lane] = first;
}

// ======================= finalize (unchanged) =======================
__global__ void finalize_kernel(const double* __restrict__ part, float* __restrict__ mr, int C){
  int o = threadIdx.x;
  if (o < C){
    double s1=0.0, s2=0.0;
    for (int k=0;k<32;k++){ s1 += part[o*32+k]; s2 += part[(C+o)*32+k]; }
    const double n = (double)NPIX;
    double mean = s1/n;
    double var  = s2/n - mean*mean;
    mr[2*o]   = (float)mean;
    mr[2*o+1] = (float)(1.0/sqrt(var + (double)EPSF));
  }
}

// ======================= tiled MLP chain =======================
// Block: 256 threads (ty=t>>4 in [0,16): 4 pixels each; tx=t&15: 4 (or 8) chans).
// 64 pixels/block, 4096 blocks. Weights transposed in LDS, activations ping-pong
// through x[ch][px] stride-68. Per-thread acc tile -> no scratch spills.
constexpr int XIN = 0;          // 6*68   = 408
constexpr int W0F = 408;        // 6*64   = 384
constexpr int B0F = 792;        // 64
constexpr int W1F = 856;        // 64*64  = 4096
constexpr int B1F = 4952;       // 64
constexpr int XBF = 5016;       // 64*68  = 4352
constexpr int SRF = 9368;       // 256  (f32 stats red, or u32 maxpool)
constexpr int W2F = 9624;       // 64*128 = 8192
constexpr int B2F = 17816;      // 128
constexpr int SM_SMALL = 9624;  // stages 1,2 (38.5 KB)
constexpr int SM_BIG   = 17944; // stages 3,4 (71.8 KB -> 2 blocks/CU)

template<int STAGE, bool STZ3>
__global__ __launch_bounds__(256,2) void mlp_kernel(
    const float* __restrict__ xyz, const float* __restrict__ pts,
    const float* __restrict__ nxyz, const int* __restrict__ grp,
    const float* __restrict__ w0, const float* __restrict__ b0,
    const float* __restrict__ mr1, const float* __restrict__ g0, const float* __restrict__ be0,
    const float* __restrict__ w1, const float* __restrict__ b1,
    const float* __restrict__ mr2, const float* __restrict__ g1, const float* __restrict__ be1,
    const float* __restrict__ w2, const float* __restrict__ b2,
    const float* __restrict__ mr3, const float* __restrict__ g2, const float* __restrict__ be2,
    double* __restrict__ part, float* __restrict__ out1, float* __restrict__ z3w)
{
  __shared__ float sm[(STAGE>=3)? SM_BIG : SM_SMALL];
  const int t   = threadIdx.x;
  const int blk = blockIdx.x;
  const int tx  = t & 15, ty = t >> 4;
  const int p0  = blk*64;
  const int slot = blk & 31;

  sm[SRF + t] = 0.0f;   // stats / maxpool slot (0.0f bits == 0u)

  for (int i=t;i<384;i+=256){ int o=i/6, c=i-o*6; sm[W0F + c*64 + o] = w0[i]; }
  if (t<64) sm[B0F+t] = b0[t];
  if constexpr (STAGE>=2){
    for (int i=t;i<4096;i+=256){ int o=i&63, c=i>>6; sm[W1F + c*64 + o] = w1[o*64+c]; }
    if (t<64) sm[B1F+t] = b1[t];
  }
  if constexpr (STAGE>=3){
    for (int i=t;i<8192;i+=256){ int o=i&127, c=i>>7; sm[W2F + c*128 + o] = w2[o*64+c]; }
    if (t<128) sm[B2F+t] = b2[t];
  }
  for (int i=t;i<384;i+=256){
    int c=i>>6, px=i&63, p=p0+px, gid=p>>5, bb=p>>14;
    int idx = grp[p];
    float v;
    if (c<3) v = __fsub_rn(xyz[(size_t)bb*3*NN + c*NN + idx], nxyz[gid*3+c]);
    else     v = pts[(size_t)bb*3*NN + (c-3)*NN + idx];
    sm[XIN + c*68 + px] = v;
  }
  __syncthreads();

  // ---- layer 1: 6 -> 64 ----
  float z[4][4];
#pragma unroll
  for (int i=0;i<4;i++)
#pragma unroll
    for (int j=0;j<4;j++) z[i][j]=0.0f;
#pragma unroll
  for (int k=0;k<6;k++){
    float4 xv = *(const float4*)&sm[XIN + k*68 + ty*4];
    float4 wv = *(const float4*)&sm[W0F + k*64 + tx*4];
    const float xs[4]={xv.x,xv.y,xv.z,xv.w};
    const float wsv[4]={wv.x,wv.y,wv.z,wv.w};
#pragma unroll
    for (int i=0;i<4;i++)
#pragma unroll
      for (int j=0;j<4;j++) z[i][j] = fmaf(xs[i], wsv[j], z[i][j]);
  }
#pragma unroll
  for (int i=0;i<4;i++)
#pragma unroll
    for (int j=0;j<4;j++) z[i][j] = __fadd_rn(z[i][j], sm[B0F + tx*4 + j]);

  if constexpr (STAGE==1){
#pragma unroll
    for (int j=0;j<4;j++){
      float s1=0.0f, s2=0.0f;
#pragma unroll
      for (int i=0;i<4;i++){ s1 = __fadd_rn(s1, z[i][j]); s2 = fmaf(z[i][j], z[i][j], s2); }
      atomicAdd(&sm[SRF + (tx*4+j)*2    ], s1);
      atomicAdd(&sm[SRF + (tx*4+j)*2 + 1], s2);
    }
    __syncthreads();
    if (t<128){ int ch=t>>1, m=t&1;
      atomicAdd(part + (size_t)((m? 64+ch : ch)*32 + slot), (double)sm[SRF+t]);
    }
    return;
  }

  if constexpr (STAGE>=2){
#pragma unroll
    for (int j=0;j<4;j++){
      int ch = tx*4+j;
      float m=mr1[2*ch], r=mr1[2*ch+1], gg=g0[ch], bt=be0[ch];
      float4 o;
      o.x = fmaxf(fmaf(__fmul_rn(__fsub_rn(z[0][j],m),r), gg, bt), 0.0f);
      o.y = fmaxf(fmaf(__fmul_rn(__fsub_rn(z[1][j],m),r), gg, bt), 0.0f);
      o.z = fmaxf(fmaf(__fmul_rn(__fsub_rn(z[2][j],m),r), gg, bt), 0.0f);
      o.w = fmaxf(fmaf(__fmul_rn(__fsub_rn(z[3][j],m),r), gg, bt), 0.0f);
      *(float4*)&sm[XBF + ch*68 + ty*4] = o;
    }
    __syncthreads();

    // ---- layer 2: 64 -> 64 ----
#pragma unroll
    for (int i=0;i<4;i++)
#pragma unroll
      for (int j=0;j<4;j++) z[i][j]=0.0f;
#pragma unroll 8
    for (int k=0;k<64;k++){
      float4 xv = *(const float4*)&sm[XBF + k*68 + ty*4];
      float4 wv = *(const float4*)&sm[W1F + k*64 + tx*4];
      const float xs[4]={xv.x,xv.y,xv.z,xv.w};
      const float wsv[4]={wv.x,wv.y,wv.z,wv.w};
#pragma unroll
      for (int i=0;i<4;i++)
#pragma unroll
        for (int j=0;j<4;j++) z[i][j] = fmaf(xs[i], wsv[j], z[i][j]);
    }
#pragma unroll
    for (int i=0;i<4;i++)
#pragma unroll
      for (int j=0;j<4;j++) z[i][j] = __fadd_rn(z[i][j], sm[B1F + tx*4 + j]);

    if constexpr (STAGE==2){
#pragma unroll
      for (int j=0;j<4;j++){
        float s1=0.0f, s2=0.0f;
#pragma unroll
        for (int i=0;i<4;i++){ s1 = __fadd_rn(s1, z[i][j]); s2 = fmaf(z[i][j], z[i][j], s2); }
        atomicAdd(&sm[SRF + (tx*4+j)*2    ], s1);
        atomicAdd(&sm[SRF + (tx*4+j)*2 + 1], s2);
      }
      __syncthreads();
      if (t<128){ int ch=t>>1, m=t&1;
        atomicAdd(part + (size_t)((m? 64+ch : ch)*32 + slot), (double)sm[SRF+t]);
      }
      return;
    }
  }

  if constexpr (STAGE>=3){
    __syncthreads();
#pragma unroll
    for (int j=0;j<4;j++){
      int ch = tx*4+j;
      float m=mr2[2*ch], r=mr2[2*ch+1], gg=g1[ch], bt=be1[ch];
      float4 o;
      o.x = fmaxf(fmaf(__fmul_rn(__fsub_rn(z[0][j],m),r), gg, bt), 0.0f);
      o.y = fmaxf(fmaf(__fmul_rn(__fsub_rn(z[1][j],m),r), gg, bt), 0.0f);
      o.z = fmaxf(fmaf(__fmul_rn(__fsub_rn(z[2][j],m),r), gg, bt), 0.0f);
      o.w = fmaxf(fmaf(__fmul_rn(__fsub_rn(z[3][j],m),r), gg, bt), 0.0f);
      *(float4*)&sm[XBF + ch*68 + ty*4] = o;
    }
    __syncthreads();

    // ---- layer 3: 64 -> 128 ----
    float a3[4][8];
#pragma unroll
    for (int i=0;i<4;i++)
#pragma unroll
      for (int j=0;j<8;j++) a3[i][j]=0.0f;
#pragma unroll 4
    for (int k=0;k<64;k++){
      float4 xv  = *(const float4*)&sm[XBF + k*68  + ty*4];
      float4 wv0 = *(const float4*)&sm[W2F + k*128 + tx*4];
      float4 wv1 = *(const float4*)&sm[W2F + k*128 + 64 + tx*4];
      const float xs[4]={xv.x,xv.y,xv.z,xv.w};
      const float wsv[8]={wv0.x,wv0.y,wv0.z,wv0.w, wv1.x,wv1.y,wv1.z,wv1.w};
#pragma unroll
      for (int i=0;i<4;i++)
#pragma unroll
        for (int j=0;j<8;j++) a3[i][j] = fmaf(xs[i], wsv[j], a3[i][j]);
    }
#pragma unroll
    for (int i=0;i<4;i++)
#pragma unroll
      for (int j=0;j<8;j++){
        int ch = (j<4)? (tx*4+j) : (64+tx*4+(j-4));
        a3[i][j] = __fadd_rn(a3[i][j], sm[B2F + ch]);
      }

    if constexpr (STAGE==3){
      if constexpr (STZ3){
#pragma unroll
        for (int i=0;i<4;i++){
          size_t p = (size_t)(p0 + ty*4 + i)*128;
          *(float4*)&z3w[p + tx*4]      = make_float4(a3[i][0],a3[i][1],a3[i][2],a3[i][3]);
          *(float4*)&z3w[p + 64 + tx*4] = make_float4(a3[i][4],a3[i][5],a3[i][6],a3[i][7]);
        }
      }
#pragma unroll
      for (int j=0;j<8;j++){
        int ch = (j<4)? (tx*4+j) : (64+tx*4+(j-4));
        float s1=0.0f, s2=0.0f;
#pragma unroll
        for (int i=0;i<4;i++){ s1 = __fadd_rn(s1, a3[i][j]); s2 = fmaf(a3[i][j], a3[i][j], s2); }
        atomicAdd(&sm[SRF + ch*2    ], s1);
        atomicAdd(&sm[SRF + ch*2 + 1], s2);
      }
      __syncthreads();
      { int ch=t>>1, m=t&1;
        atomicAdd(part + (size_t)((m? 128+ch : ch)*32 + slot), (double)sm[SRF+t]);
      }
      return;
    }

    if constexpr (STAGE==4){
      const int grp_l = ty>>3;
      unsigned* omax = (unsigned*)sm;
#pragma unroll
      for (int j=0;j<8;j++){
        int ch = (j<4)? (tx*4+j) : (64+tx*4+(j-4));
        float m=mr3[2*ch], r=mr3[2*ch+1], gg=g2[ch], bt=be2[ch];
        float vmax=0.0f;
#pragma unroll
        for (int i=0;i<4;i++){
          float v = fmaxf(fmaf(__fmul_rn(__fsub_rn(a3[i][j],m),r), gg, bt), 0.0f);
          vmax = fmaxf(vmax, v);
        }
        atomicMax(&omax[SRF + grp_l*128 + ch], __float_as_uint(vmax));
      }
      __syncthreads();
      { int g = t>>7, o = t&127;
        int gid = blk*2 + g, bb = gid>>9, s = gid&511;
        out1[((size_t)(bb*128+o))*512 + s] = __uint_as_float(omax[SRF + t]);
      }
    }
  }
}

// ======================= maxpool reader (fast stage-4 when z3 stored) =======================
__global__ __launch_bounds__(256) void maxpool_kernel(const float* __restrict__ z3,
        const float* __restrict__ mr3, const float* __restrict__ g2,
        const float* __restrict__ be2, float* __restrict__ out1){
  const int t = threadIdx.x;
  const int g = blockIdx.x*2 + (t>>7);     // group id (b*SS+s)
  const int o = t & 127;
  const int bb = g >> 9, s = g & 511;
  const float* zp = z3 + (size_t)g*KK*128 + o;
  float m=mr3[2*o], r=mr3[2*o+1], gg=g2[o], bt=be2[o];
  float mx = 0.0f;                         // relu outputs are >= 0
#pragma unroll 8
  for (int k=0;k<KK;k++){
    float v = fmaxf(fmaf(__fmul_rn(__fsub_rn(zp[(size_t)k*128],m),r), gg, bt), 0.0f);
    mx = fmaxf(mx, v);
  }
  out1[((size_t)(bb*128+o))*SS + s] = mx;
}

// ======================= launch =======================
extern "C" void kernel_launch(void* const* d_in, const int* in_sizes, int n_in,
                              void* d_out, int out_size, void* d_ws, size_t ws_size,
                              hipStream_t stream){
  const float* xyz = (const float*)d_in[0];
  const float* pts = (const float*)d_in[1];
  const float* w0  = (const float*)d_in[2];  const float* b0  = (const float*)d_in[3];
  const float* g0  = (const float*)d_in[4];  const float* be0 = (const float*)d_in[5];
  const float* w1  = (const float*)d_in[6];  const float* b1  = (const float*)d_in[7];
  const float* g1  = (const float*)d_in[8];  const float* be1 = (const float*)d_in[9];
  const float* w2  = (const float*)d_in[10]; const float* b2  = (const float*)d_in[11];
  const float* g2  = (const float*)d_in[12]; const float* be2 = (const float*)d_in[13];

  float* out  = (float*)d_out;
  float* out1 = out + BB*3*SS;
  char*  ws   = (char*)d_ws;

  float*  nxyz = (float*)(ws + OFF_NXYZ);
  int*    grp  = (int*)  (ws + OFF_GRP);
  double* p1   = (double*)(ws + OFF_P1);
  double* p2   = (double*)(ws + OFF_P2);
  double* p3   = (double*)(ws + OFF_P3);
  float*  mr1  = (float*)(ws + OFF_MR1);
  float*  mr2  = (float*)(ws + OFF_MR2);
  float*  mr3  = (float*)(ws + OFF_MR3);
  float*  z3w  = (float*)(ws + OFF_Z3);

  const bool stz3 = (ws_size >= OFF_Z3 + Z3SZ);

  hipMemsetAsync(ws + OFF_P1, 0, 32768+32768+65536, stream);

  fps_kernel <<<BB, 512, 0, stream>>>(xyz, out, nxyz);
  ball_kernel<<<NGRP*64/256, 256, 0, stream>>>(xyz, nxyz, grp);

#define MLP_ARGS xyz, pts, nxyz, grp, w0, b0, mr1, g0, be0, w1, b1, mr2, g1, be1, w2, b2, mr3, g2, be2
  mlp_kernel<1,false><<<NPIX/64, 256, 0, stream>>>(MLP_ARGS, p1, out1, z3w);
  finalize_kernel<<<1,128,0,stream>>>(p1, mr1, 64);
  mlp_kernel<2,false><<<NPIX/64, 256, 0, stream>>>(MLP_ARGS, p2, out1, z3w);
  finalize_kernel<<<1,128,0,stream>>>(p2, mr2, 64);
  if (stz3){
    mlp_kernel<3,true><<<NPIX/64, 256, 0, stream>>>(MLP_ARGS, p3, out1, z3w);
    finalize_kernel<<<1,128,0,stream>>>(p3, mr3, 128);
    maxpool_kernel<<<NGRP/2, 256, 0, stream>>>(z3w, mr3, g2, be2, out1);
  } else {
    mlp_kernel<3,false><<<NPIX/64, 256, 0, stream>>>(MLP_ARGS, p3, out1, z3w);
    finalize_kernel<<<1,128,0,stream>>>(p3, mr3, 128);
    mlp_kernel<4,false><<<NPIX/64, 256, 0, stream>>>(MLP_ARGS, p3, out1, z3w);
  }
#undef MLP_ARGS
}

// Round 6
// 854.496 us; speedup vs baseline: 11.8488x; 1.0842x over previous
//
#include <hip/hip_runtime.h>
#include <math.h>

#define BB 16
#define NN 4096
#define SS 512
#define KK 32
#define NPIX (BB*SS*KK)          /* 262144 pixels (b,s,k) */
#define NGRP (BB*SS)             /* 8192 groups */

static constexpr float R2F  = (float)0.16000000000000003;  // RADIUS**2 as f32
static constexpr float EPSF = 1e-5f;

// ---------------- workspace layout (bytes) ----------------
constexpr size_t OFF_NXYZ = 0;                     // B*S*3 f32  = 98304
constexpr size_t OFF_GRP  = 98304;                 // B*S*NS i32 = 1048576
constexpr size_t OFF_P1   = 98304 + 1048576;       // 2*64*32 f64  = 32768
constexpr size_t OFF_P2   = OFF_P1 + 32768;
constexpr size_t OFF_P3   = OFF_P2 + 32768;        // 2*128*32 f64 = 65536
constexpr size_t OFF_MR1  = OFF_P3 + 65536;        // 64*2 f32
constexpr size_t OFF_MR2  = OFF_MR1 + 512;
constexpr size_t OFF_MR3  = OFF_MR2 + 512;         // 128*2 f32
constexpr size_t OFF_Z3   = 2*1024*1024;
constexpr size_t Z3SZ     = (size_t)NPIX*128*4;    // 134217728

// DPP wave64 reduction steps: row_shr:1,2,4,8 then row_bcast:15, row_bcast:31.
// Invalid lanes return `old` (= current value) -> no-op combine. Result lane 63.
#define DPP_FMAX(v, ctrl) { int _t = __builtin_amdgcn_update_dpp(              \
      __float_as_int(v), __float_as_int(v), ctrl, 0xf, 0xf, false);            \
      v = fmaxf(v, __int_as_float(_t)); }
#define DPP_UMIN(v, ctrl) { unsigned _t = (unsigned)__builtin_amdgcn_update_dpp( \
      (int)(v), (int)(v), ctrl, 0xf, 0xf, false);                              \
      v = (v < _t ? v : _t); }

// ======================= FPS =======================
// 256 threads (4 waves), 16 pts/thread. Round-6 change: DPP-based reduction.
//  - inner loop tracks only the running max (no index select): 10 VALU/pt.
//  - wave argmax: DPP f32 max-reduce (6 in-VALU ops, lane 63) + readlane
//    broadcast, then a 16-step equality scan (descending j -> lowest index,
//    exact argmax tie-break) + DPP u32 min-reduce of the index.
//  - replaces the 6-level u64 __shfl_xor chain (12 dependent ds_bpermute_b32
//    through the LDS pipe) with ~12 VALU-latency DPP ops.
//  - cross-wave: 4 packed u64 slots (wave_vmax hi, ~wave_minidx lo), read as
//    2x ds_read_b128; u64 max == (max dist, lowest index) — same verified
//    semantics as before.
__global__ __launch_bounds__(256) void fps_kernel(const float* __restrict__ xyz,
        float* __restrict__ out0, float* __restrict__ nxyz){
  const int b = blockIdx.x;
  const float* xb = xyz + (size_t)b*3*NN;
  __shared__ float4 pt4[NN];                       // 64 KB
  __shared__ __align__(16) unsigned long long skey[2][4];
  __shared__ int hist[SS];
  const int t = threadIdx.x;
  const int lane = t & 63, wv = t >> 6;
  float rx[16], ry[16], rz[16], rd[16];
#pragma unroll
  for (int j=0;j<16;j++){
    int i = t + 256*j;
    float x = xb[i], y = xb[NN+i], z = xb[2*NN+i];
    rx[j]=x; ry[j]=y; rz[j]=z;
    pt4[i] = make_float4(x,y,z,0.0f);
    rd[j]=1e10f;
  }
  __syncthreads();
  int far = 0;
  for (int s=0;s<SS;s++){
    const int buf = s & 1;
    float4 c = pt4[far];
    if (t==0) hist[s] = far;
    float bv = -1.0f;
#pragma unroll
    for (int j=0;j<16;j++){
      float dx=__fsub_rn(rx[j],c.x), dy=__fsub_rn(ry[j],c.y), dz=__fsub_rn(rz[j],c.z);
      float d2=__fadd_rn(__fadd_rn(__fmul_rn(dx,dx),__fmul_rn(dy,dy)),__fmul_rn(dz,dz));
      float nd=fminf(rd[j],d2);
      rd[j]=nd;
      bv = fmaxf(bv, nd);
    }
    // wave max of bv (result in lane 63), broadcast via readlane
    DPP_FMAX(bv,0x111); DPP_FMAX(bv,0x112); DPP_FMAX(bv,0x114);
    DPP_FMAX(bv,0x118); DPP_FMAX(bv,0x142); DPP_FMAX(bv,0x143);
    const float vmax = __int_as_float(__builtin_amdgcn_readlane(__float_as_int(bv), 63));
    // lane-local lowest matching index (descending j: last write = lowest idx)
    unsigned cand = 0xFFFFFFFFu;
#pragma unroll
    for (int j=15;j>=0;j--) if (rd[j]==vmax) cand = (unsigned)(t+256*j);
    // wave min of cand (result in lane 63)
    DPP_UMIN(cand,0x111); DPP_UMIN(cand,0x112); DPP_UMIN(cand,0x114);
    DPP_UMIN(cand,0x118); DPP_UMIN(cand,0x142); DPP_UMIN(cand,0x143);
    if (lane==63){
      skey[buf][wv] = ((unsigned long long)(unsigned)__float_as_int(vmax) << 32)
                    | (unsigned)(~cand);
    }
    __syncthreads();   // only lgkm traffic outstanding -> cheap drain
    unsigned long long k0=skey[buf][0], k1=skey[buf][1], k2=skey[buf][2], k3=skey[buf][3];
    unsigned long long m01 = (k0>k1)?k0:k1, m23 = (k2>k3)?k2:k3;
    unsigned long long m   = (m01>m23)?m01:m23;
    far = (int)(~(unsigned)(m & 0xFFFFFFFFull));
    // no WAR barrier: skey[buf] rewritten at step s+2, after step s+1's barrier
  }
  __syncthreads();
  // cooperative writeout (once)
  for (int s=t;s<SS;s+=256){
    int idx = hist[s];
    float4 c = pt4[idx];
    int gid = b*SS + s;
    nxyz[gid*3+0]=c.x; nxyz[gid*3+1]=c.y; nxyz[gid*3+2]=c.z;
    out0[(b*3+0)*SS+s]=c.x; out0[(b*3+1)*SS+s]=c.y; out0[(b*3+2)*SS+s]=c.z;
  }
}

// ======================= ball query (unchanged, passing) =======================
__global__ __launch_bounds__(256) void ball_kernel(const float* __restrict__ xyz,
        const float* __restrict__ nxyz, int* __restrict__ grp){
  const int gw   = (blockIdx.x*256 + threadIdx.x) >> 6;
  const int lane = threadIdx.x & 63;
  if (gw >= NGRP) return;
  const int b = gw / SS;
  const float* xb = xyz + (size_t)b*3*NN;
  const float nx=nxyz[gw*3+0], ny=nxyz[gw*3+1], nz=nxyz[gw*3+2];
  const float sn = __fadd_rn(__fadd_rn(__fmul_rn(nx,nx),__fmul_rn(ny,ny)),__fmul_rn(nz,nz));
  int cnt=0, first=-1;
  int* g = grp + (size_t)gw*KK;
  for (int c=0;c<NN/64 && cnt<KK;c++){
    int i=c*64+lane;
    float x=xb[i], y=xb[NN+i], z=xb[2*NN+i];
    float sxx=__fadd_rn(__fadd_rn(__fmul_rn(x,x),__fmul_rn(y,y)),__fmul_rn(z,z));
    float dot=__fadd_rn(__fadd_rn(__fmul_rn(nx,x),__fmul_rn(ny,y)),__fmul_rn(nz,z));
    float sqr=__fsub_rn(__fadd_rn(sn,sxx),__fmul_rn(2.0f,dot));
    bool m = (sqr <= R2F);
    unsigned long long mask = __ballot(m);
    if (m){
      int pos = cnt + __popcll(mask & ((1ull<<lane)-1ull));
      if (pos < KK) g[pos] = i;
    }
    if (first<0 && mask) first = c*64 + (__ffsll((long long)mask) - 1);
    cnt += __popcll(mask);
  }
  if (cnt < KK && lane >= cnt && lane < KK) g[lane] = first;
}

// ======================= finalize (unchanged) =======================
__global__ void finalize_kernel(const double* __restrict__ part, float* __restrict__ mr, int C){
  int o = threadIdx.x;
  if (o < C){
    double s1=0.0, s2=0.0;
    for (int k=0;k<32;k++){ s1 += part[o*32+k]; s2 += part[(C+o)*32+k]; }
    const double n = (double)NPIX;
    double mean = s1/n;
    double var  = s2/n - mean*mean;
    mr[2*o]   = (float)mean;
    mr[2*o+1] = (float)(1.0/sqrt(var + (double)EPSF));
  }
}

// ======================= tiled MLP chain (unchanged, passing) =======================
constexpr int XIN = 0;          // 6*68   = 408
constexpr int W0F = 408;        // 6*64   = 384
constexpr int B0F = 792;        // 64
constexpr int W1F = 856;        // 64*64  = 4096
constexpr int B1F = 4952;       // 64
constexpr int XBF = 5016;       // 64*68  = 4352
constexpr int SRF = 9368;       // 256  (f32 stats red, or u32 maxpool)
constexpr int W2F = 9624;       // 64*128 = 8192
constexpr int B2F = 17816;      // 128
constexpr int SM_SMALL = 9624;  // stages 1,2 (38.5 KB)
constexpr int SM_BIG   = 17944; // stages 3,4 (71.8 KB -> 2 blocks/CU)

template<int STAGE, bool STZ3>
__global__ __launch_bounds__(256,2) void mlp_kernel(
    const float* __restrict__ xyz, const float* __restrict__ pts,
    const float* __restrict__ nxyz, const int* __restrict__ grp,
    const float* __restrict__ w0, const float* __restrict__ b0,
    const float* __restrict__ mr1, const float* __restrict__ g0, const float* __restrict__ be0,
    const float* __restrict__ w1, const float* __restrict__ b1,
    const float* __restrict__ mr2, const float* __restrict__ g1, const float* __restrict__ be1,
    const float* __restrict__ w2, const float* __restrict__ b2,
    const float* __restrict__ mr3, const float* __restrict__ g2, const float* __restrict__ be2,
    double* __restrict__ part, float* __restrict__ out1, float* __restrict__ z3w)
{
  __shared__ float sm[(STAGE>=3)? SM_BIG : SM_SMALL];
  const int t   = threadIdx.x;
  const int blk = blockIdx.x;
  const int tx  = t & 15, ty = t >> 4;
  const int p0  = blk*64;
  const int slot = blk & 31;

  sm[SRF + t] = 0.0f;   // stats / maxpool slot (0.0f bits == 0u)

  for (int i=t;i<384;i+=256){ int o=i/6, c=i-o*6; sm[W0F + c*64 + o] = w0[i]; }
  if (t<64) sm[B0F+t] = b0[t];
  if constexpr (STAGE>=2){
    for (int i=t;i<4096;i+=256){ int o=i&63, c=i>>6; sm[W1F + c*64 + o] = w1[o*64+c]; }
    if (t<64) sm[B1F+t] = b1[t];
  }
  if constexpr (STAGE>=3){
    for (int i=t;i<8192;i+=256){ int o=i&127, c=i>>7; sm[W2F + c*128 + o] = w2[o*64+c]; }
    if (t<128) sm[B2F+t] = b2[t];
  }
  for (int i=t;i<384;i+=256){
    int c=i>>6, px=i&63, p=p0+px, gid=p>>5, bb=p>>14;
    int idx = grp[p];
    float v;
    if (c<3) v = __fsub_rn(xyz[(size_t)bb*3*NN + c*NN + idx], nxyz[gid*3+c]);
    else     v = pts[(size_t)bb*3*NN + (c-3)*NN + idx];
    sm[XIN + c*68 + px] = v;
  }
  __syncthreads();

  // ---- layer 1: 6 -> 64 ----
  float z[4][4];
#pragma unroll
  for (int i=0;i<4;i++)
#pragma unroll
    for (int j=0;j<4;j++) z[i][j]=0.0f;
#pragma unroll
  for (int k=0;k<6;k++){
    float4 xv = *(const float4*)&sm[XIN + k*68 + ty*4];
    float4 wv = *(const float4*)&sm[W0F + k*64 + tx*4];
    const float xs[4]={xv.x,xv.y,xv.z,xv.w};
    const float wsv[4]={wv.x,wv.y,wv.z,wv.w};
#pragma unroll
    for (int i=0;i<4;i++)
#pragma unroll
      for (int j=0;j<4;j++) z[i][j] = fmaf(xs[i], wsv[j], z[i][j]);
  }
#pragma unroll
  for (int i=0;i<4;i++)
#pragma unroll
    for (int j=0;j<4;j++) z[i][j] = __fadd_rn(z[i][j], sm[B0F + tx*4 + j]);

  if constexpr (STAGE==1){
#pragma unroll
    for (int j=0;j<4;j++){
      float s1=0.0f, s2=0.0f;
#pragma unroll
      for (int i=0;i<4;i++){ s1 = __fadd_rn(s1, z[i][j]); s2 = fmaf(z[i][j], z[i][j], s2); }
      atomicAdd(&sm[SRF + (tx*4+j)*2    ], s1);
      atomicAdd(&sm[SRF + (tx*4+j)*2 + 1], s2);
    }
    __syncthreads();
    if (t<128){ int ch=t>>1, m=t&1;
      atomicAdd(part + (size_t)((m? 64+ch : ch)*32 + slot), (double)sm[SRF+t]);
    }
    return;
  }

  if constexpr (STAGE>=2){
#pragma unroll
    for (int j=0;j<4;j++){
      int ch = tx*4+j;
      float m=mr1[2*ch], r=mr1[2*ch+1], gg=g0[ch], bt=be0[ch];
      float4 o;
      o.x = fmaxf(fmaf(__fmul_rn(__fsub_rn(z[0][j],m),r), gg, bt), 0.0f);
      o.y = fmaxf(fmaf(__fmul_rn(__fsub_rn(z[1][j],m),r), gg, bt), 0.0f);
      o.z = fmaxf(fmaf(__fmul_rn(__fsub_rn(z[2][j],m),r), gg, bt), 0.0f);
      o.w = fmaxf(fmaf(__fmul_rn(__fsub_rn(z[3][j],m),r), gg, bt), 0.0f);
      *(float4*)&sm[XBF + ch*68 + ty*4] = o;
    }
    __syncthreads();

    // ---- layer 2: 64 -> 64 ----
#pragma unroll
    for (int i=0;i<4;i++)
#pragma unroll
      for (int j=0;j<4;j++) z[i][j]=0.0f;
#pragma unroll 8
    for (int k=0;k<64;k++){
      float4 xv = *(const float4*)&sm[XBF + k*68 + ty*4];
      float4 wv = *(const float4*)&sm[W1F + k*64 + tx*4];
      const float xs[4]={xv.x,xv.y,xv.z,xv.w};
      const float wsv[4]={wv.x,wv.y,wv.z,wv.w};
#pragma unroll
      for (int i=0;i<4;i++)
#pragma unroll
        for (int j=0;j<4;j++) z[i][j] = fmaf(xs[i], wsv[j], z[i][j]);
    }
#pragma unroll
    for (int i=0;i<4;i++)
#pragma unroll
      for (int j=0;j<4;j++) z[i][j] = __fadd_rn(z[i][j], sm[B1F + tx*4 + j]);

    if constexpr (STAGE==2){
#pragma unroll
      for (int j=0;j<4;j++){
        float s1=0.0f, s2=0.0f;
#pragma unroll
        for (int i=0;i<4;i++){ s1 = __fadd_rn(s1, z[i][j]); s2 = fmaf(z[i][j], z[i][j], s2); }
        atomicAdd(&sm[SRF + (tx*4+j)*2    ], s1);
        atomicAdd(&sm[SRF + (tx*4+j)*2 + 1], s2);
      }
      __syncthreads();
      if (t<128){ int ch=t>>1, m=t&1;
        atomicAdd(part + (size_t)((m? 64+ch : ch)*32 + slot), (double)sm[SRF+t]);
      }
      return;
    }
  }

  if constexpr (STAGE>=3){
    __syncthreads();
#pragma unroll
    for (int j=0;j<4;j++){
      int ch = tx*4+j;
      float m=mr2[2*ch], r=mr2[2*ch+1], gg=g1[ch], bt=be1[ch];
      float4 o;
      o.x = fmaxf(fmaf(__fmul_rn(__fsub_rn(z[0][j],m),r), gg, bt), 0.0f);
      o.y = fmaxf(fmaf(__fmul_rn(__fsub_rn(z[1][j],m),r), gg, bt), 0.0f);
      o.z = fmaxf(fmaf(__fmul_rn(__fsub_rn(z[2][j],m),r), gg, bt), 0.0f);
      o.w = fmaxf(fmaf(__fmul_rn(__fsub_rn(z[3][j],m),r), gg, bt), 0.0f);
      *(float4*)&sm[XBF + ch*68 + ty*4] = o;
    }
    __syncthreads();

    // ---- layer 3: 64 -> 128 ----
    float a3[4][8];
#pragma unroll
    for (int i=0;i<4;i++)
#pragma unroll
      for (int j=0;j<8;j++) a3[i][j]=0.0f;
#pragma unroll 4
    for (int k=0;k<64;k++){
      float4 xv  = *(const float4*)&sm[XBF + k*68  + ty*4];
      float4 wv0 = *(const float4*)&sm[W2F + k*128 + tx*4];
      float4 wv1 = *(const float4*)&sm[W2F + k*128 + 64 + tx*4];
      const float xs[4]={xv.x,xv.y,xv.z,xv.w};
      const float wsv[8]={wv0.x,wv0.y,wv0.z,wv0.w, wv1.x,wv1.y,wv1.z,wv1.w};
#pragma unroll
      for (int i=0;i<4;i++)
#pragma unroll
        for (int j=0;j<8;j++) a3[i][j] = fmaf(xs[i], wsv[j], a3[i][j]);
    }
#pragma unroll
    for (int i=0;i<4;i++)
#pragma unroll
      for (int j=0;j<8;j++){
        int ch = (j<4)? (tx*4+j) : (64+tx*4+(j-4));
        a3[i][j] = __fadd_rn(a3[i][j], sm[B2F + ch]);
      }

    if constexpr (STAGE==3){
      if constexpr (STZ3){
#pragma unroll
        for (int i=0;i<4;i++){
          size_t p = (size_t)(p0 + ty*4 + i)*128;
          *(float4*)&z3w[p + tx*4]      = make_float4(a3[i][0],a3[i][1],a3[i][2],a3[i][3]);
          *(float4*)&z3w[p + 64 + tx*4] = make_float4(a3[i][4],a3[i][5],a3[i][6],a3[i][7]);
        }
      }
#pragma unroll
      for (int j=0;j<8;j++){
        int ch = (j<4)? (tx*4+j) : (64+tx*4+(j-4));
        float s1=0.0f, s2=0.0f;
#pragma unroll
        for (int i=0;i<4;i++){ s1 = __fadd_rn(s1, a3[i][j]); s2 = fmaf(a3[i][j], a3[i][j], s2); }
        atomicAdd(&sm[SRF + ch*2    ], s1);
        atomicAdd(&sm[SRF + ch*2 + 1], s2);
      }
      __syncthreads();
      { int ch=t>>1, m=t&1;
        atomicAdd(part + (size_t)((m? 128+ch : ch)*32 + slot), (double)sm[SRF+t]);
      }
      return;
    }

    if constexpr (STAGE==4){
      const int grp_l = ty>>3;
      unsigned* omax = (unsigned*)sm;
#pragma unroll
      for (int j=0;j<8;j++){
        int ch = (j<4)? (tx*4+j) : (64+tx*4+(j-4));
        float m=mr3[2*ch], r=mr3[2*ch+1], gg=g2[ch], bt=be2[ch];
        float vmax=0.0f;
#pragma unroll
        for (int i=0;i<4;i++){
          float v = fmaxf(fmaf(__fmul_rn(__fsub_rn(a3[i][j],m),r), gg, bt), 0.0f);
          vmax = fmaxf(vmax, v);
        }
        atomicMax(&omax[SRF + grp_l*128 + ch], __float_as_uint(vmax));
      }
      __syncthreads();
      { int g = t>>7, o = t&127;
        int gid = blk*2 + g, bb = gid>>9, s = gid&511;
        out1[((size_t)(bb*128+o))*512 + s] = __uint_as_float(omax[SRF + t]);
      }
    }
  }
}

// ======================= maxpool reader (unchanged, passing) =======================
__global__ __launch_bounds__(256) void maxpool_kernel(const float* __restrict__ z3,
        const float* __restrict__ mr3, const float* __restrict__ g2,
        const float* __restrict__ be2, float* __restrict__ out1){
  const int t = threadIdx.x;
  const int g = blockIdx.x*2 + (t>>7);     // group id (b*SS+s)
  const int o = t & 127;
  const int bb = g >> 9, s = g & 511;
  const float* zp = z3 + (size_t)g*KK*128 + o;
  float m=mr3[2*o], r=mr3[2*o+1], gg=g2[o], bt=be2[o];
  float mx = 0.0f;                         // relu outputs are >= 0
#pragma unroll 8
  for (int k=0;k<KK;k++){
    float v = fmaxf(fmaf(__fmul_rn(__fsub_rn(zp[(size_t)k*128],m),r), gg, bt), 0.0f);
    mx = fmaxf(mx, v);
  }
  out1[((size_t)(bb*128+o))*SS + s] = mx;
}

// ======================= launch =======================
extern "C" void kernel_launch(void* const* d_in, const int* in_sizes, int n_in,
                              void* d_out, int out_size, void* d_ws, size_t ws_size,
                              hipStream_t stream){
  const float* xyz = (const float*)d_in[0];
  const float* pts = (const float*)d_in[1];
  const float* w0  = (const float*)d_in[2];  const float* b0  = (const float*)d_in[3];
  const float* g0  = (const float*)d_in[4];  const float* be0 = (const float*)d_in[5];
  const float* w1  = (const float*)d_in[6];  const float* b1  = (const float*)d_in[7];
  const float* g1  = (const float*)d_in[8];  const float* be1 = (const float*)d_in[9];
  const float* w2  = (const float*)d_in[10]; const float* b2  = (const float*)d_in[11];
  const float* g2  = (const float*)d_in[12]; const float* be2 = (const float*)d_in[13];

  float* out  = (float*)d_out;
  float* out1 = out + BB*3*SS;
  char*  ws   = (char*)d_ws;

  float*  nxyz = (float*)(ws + OFF_NXYZ);
  int*    grp  = (int*)  (ws + OFF_GRP);
  double* p1   = (double*)(ws + OFF_P1);
  double* p2   = (double*)(ws + OFF_P2);
  double* p3   = (double*)(ws + OFF_P3);
  float*  mr1  = (float*)(ws + OFF_MR1);
  float*  mr2  = (float*)(ws + OFF_MR2);
  float*  mr3  = (float*)(ws + OFF_MR3);
  float*  z3w  = (float*)(ws + OFF_Z3);

  const bool stz3 = (ws_size >= OFF_Z3 + Z3SZ);

  hipMemsetAsync(ws + OFF_P1, 0, 32768+32768+65536, stream);

  fps_kernel <<<BB, 256, 0, stream>>>(xyz, out, nxyz);
  ball_kernel<<<NGRP*64/256, 256, 0, stream>>>(xyz, nxyz, grp);

#define MLP_ARGS xyz, pts, nxyz, grp, w0, b0, mr1, g0, be0, w1, b1, mr2, g1, be1, w2, b2, mr3, g2, be2
  mlp_kernel<1,false><<<NPIX/64, 256, 0, stream>>>(MLP_ARGS, p1, out1, z3w);
  finalize_kernel<<<1,128,0,stream>>>(p1, mr1, 64);
  mlp_kernel<2,false><<<NPIX/64, 256, 0, stream>>>(MLP_ARGS, p2, out1, z3w);
  finalize_kernel<<<1,128,0,stream>>>(p2, mr2, 64);
  if (stz3){
    mlp_kernel<3,true><<<NPIX/64, 256, 0, stream>>>(MLP_ARGS, p3, out1, z3w);
    finalize_kernel<<<1,128,0,stream>>>(p3, mr3, 128);
    maxpool_kernel<<<NGRP/2, 256, 0, stream>>>(z3w, mr3, g2, be2, out1);
  } else {
    mlp_kernel<3,false><<<NPIX/64, 256, 0, stream>>>(MLP_ARGS, p3, out1, z3w);
    finalize_kernel<<<1,128,0,stream>>>(p3, mr3, 128);
    mlp_kernel<4,false><<<NPIX/64, 256, 0, stream>>>(MLP_ARGS, p3, out1, z3w);
  }
#undef MLP_ARGS
}